// Round 4
// baseline (348.798 us; speedup 1.0000x reference)
//
#include <hip/hip_runtime.h>
#include <hip/hip_bf16.h>

// Problem constants (from reference)
#define N_NODES 100000
#define FEAT    256
#define HID     128
#define REL     2
#define BATCH   20000
#define KNEI    10

// GEMM-H geometry: H[N_NODES][384] = features[N_NODES][256] @ Wall[256][384]
// Wall cols 0:128 = W_det[0:256]; cols 128+128r = (W_stc[r] @ W_det[256+128r:...]) / K
#define NCOL 384            // 24 n-tiles of 16
#define NT   24
#define KT   8              // 256 / 32
#define ASTRIDE 264         // 256 + 8 shorts pad -> uniform LDS bank spread for b128 reads

typedef short bf16x8 __attribute__((ext_vector_type(8)));
typedef float f32x4  __attribute__((ext_vector_type(4)));

__device__ __forceinline__ unsigned short f2bf(float x) {
    union { float f; unsigned u; } v; v.f = x;
    unsigned r = v.u + 0x7fffu + ((v.u >> 16) & 1u);   // RNE
    return (unsigned short)(r >> 16);
}

__device__ __forceinline__ ushort4 pack4(float a, float b, float c, float d) {
    ushort4 p; p.x = f2bf(a); p.y = f2bf(b); p.z = f2bf(c); p.w = f2bf(d);
    return p;
}

// Swizzled index for logical (k in [0,256), n in [0,384)):
// lane reads 16B contiguous: Bsw[((kt*NT+nt)*64 + lane)*8 + j]
__device__ __forceinline__ size_t bsw_index(int k, int n) {
    int kt = k >> 5, j = k & 7, hi = (k >> 3) & 3;
    int lane = hi * 16 + (n & 15), nt = n >> 4;
    return ((size_t)(kt * NT + nt) * 64 + lane) * 8 + j;
}

// ---------------------------------------------------------------------------
// prep_W: build Wall[256][384] bf16 in MFMA B-swizzled layout.
// blocks 0..31 : cols 128+128r: (W_stc[r] @ W_det[256+128r : 256+128(r+1)]) * (1/K)
// blocks 32..33: cols 0:128   : copy of W_det rows 0..255
// ---------------------------------------------------------------------------
__global__ __launch_bounds__(256) void prep_W(const float* __restrict__ W_stc,
                                              const float* __restrict__ W_det,
                                              unsigned short* __restrict__ Bsw) {
    const int blk = blockIdx.x;
    const int tid = threadIdx.x;
    if (blk < 32) {
        const int rel   = blk >> 4;
        const int fbase = (blk & 15) * 16;
        const int n     = tid & 127;             // col within the 128-wide rel block
        const int fh    = tid >> 7;              // 0..1
        const float* wd = W_det + (size_t)(256 + rel * HID) * HID + n;  // column base
        const float scale = 1.0f / (float)KNEI;  // fold the neighbor mean here
        #pragma unroll
        for (int fo = 0; fo < 8; ++fo) {
            const int f = fbase + fh * 8 + fo;
            const float* ws = W_stc + (size_t)(rel * FEAT + f) * HID;
            float acc = 0.f;
            #pragma unroll 8
            for (int j2 = 0; j2 < HID; ++j2) acc += ws[j2] * wd[(size_t)j2 * HID];
            Bsw[bsw_index(f, 128 + rel * 128 + n)] = f2bf(acc * scale);
        }
    } else {
        const int base = (blk - 32) * 16384;     // 2 blocks x 16384 elems = 256*128
        #pragma unroll 4
        for (int i = 0; i < 64; ++i) {
            const int idx = base + i * 256 + tid;  // < 32768
            const int k = idx >> 7, n = idx & 127;
            Bsw[bsw_index(k, n)] = f2bf(W_det[idx]);
        }
    }
}

// ---------------------------------------------------------------------------
// gemm_H: H[100000][384] bf16 = features[100000][256] fp32 @ Wall (bf16, swizzled).
// Block = 256 thr (4 waves) = 64 rows. Wave w owns m-tile w (16 rows) x all 24
// n-tiles. A staged in LDS (fp32->bf16, padded stride). B fragments read
// straight from global (192 KB, L1/L2 resident). acc = 24 x f32x4 = 96 VGPRs.
// ---------------------------------------------------------------------------
__global__ __launch_bounds__(256, 2) void gemm_H(const float* __restrict__ features,
                                                 const unsigned short* __restrict__ Bsw,
                                                 unsigned short* __restrict__ H) {
    __shared__ unsigned short Asm[64 * ASTRIDE];   // 33792 B

    const int row0 = blockIdx.x * 64;
    const int tid  = threadIdx.x;
    const float4* F4 = (const float4*)features;

    // Stage A: 64 rows x 64 float4, coalesced; clamp tail rows.
    #pragma unroll
    for (int i = 0; i < 16; ++i) {
        const int idx = i * 256 + tid;           // < 4096
        const int r   = idx >> 6;
        const int c4  = idx & 63;
        int rg = row0 + r;
        if (rg >= N_NODES) rg = N_NODES - 1;
        float4 v = F4[(size_t)rg * 64 + c4];
        *(ushort4*)(Asm + r * ASTRIDE + c4 * 4) = pack4(v.x, v.y, v.z, v.w);
    }
    __syncthreads();

    const int w    = tid >> 6;
    const int lane = tid & 63;
    const int quad = lane >> 4;
    const int l16  = lane & 15;
    const unsigned short* a_base = Asm + (w * 16 + l16) * ASTRIDE + quad * 8;

    f32x4 acc[NT];
    #pragma unroll
    for (int nt = 0; nt < NT; ++nt) acc[nt] = (f32x4){0.f, 0.f, 0.f, 0.f};

    #pragma unroll
    for (int kt = 0; kt < KT; ++kt) {
        bf16x8 a = *(const bf16x8*)(a_base + kt * 32);
        const unsigned short* bk = Bsw + ((size_t)kt * NT * 64 + lane) * 8;
        #pragma unroll
        for (int nt = 0; nt < NT; ++nt) {
            bf16x8 bfr = *(const bf16x8*)(bk + (size_t)nt * 64 * 8);
            acc[nt] = __builtin_amdgcn_mfma_f32_16x16x32_bf16(a, bfr, acc[nt], 0, 0, 0);
        }
    }

    // Store H rows (bf16). C/D layout: col = l16, row = quad*4 + r.
    const int rbase = row0 + w * 16 + quad * 4;
    #pragma unroll
    for (int r = 0; r < 4; ++r) {
        const int row = rbase + r;
        if (row < N_NODES) {
            unsigned short* hrow = H + (size_t)row * NCOL + l16;
            #pragma unroll
            for (int nt = 0; nt < NT; ++nt)
                hrow[nt * 16] = f2bf(acc[nt][r]);
        }
    }
}

// ---------------------------------------------------------------------------
// gather_out: out[b] = relu( H[self, 0:128] + sum_k H[idx0_k, 128:256]
//                                           + sum_k H[idx1_k, 256:384] )
// (mean scale already folded into Wall). One wave per batch element; lane owns
// one dword (2 bf16 cols); each gather = 64 lanes x 4B = 256B coalesced chunk.
// ---------------------------------------------------------------------------
__global__ __launch_bounds__(256) void gather_out(const int* __restrict__ nodes,
                                                  const int* __restrict__ neigh_idx,
                                                  const unsigned short* __restrict__ H,
                                                  float* __restrict__ out) {
    const int w    = threadIdx.x >> 6;
    const int lane = threadIdx.x & 63;
    const int b    = blockIdx.x * 4 + w;
    if (b >= BATCH) return;

    const unsigned* Hd = (const unsigned*)H;       // row = 192 dwords
    const int self = nodes[b];
    const int* i0 = neigh_idx + (size_t)b * KNEI;
    const int* i1 = neigh_idx + (size_t)(BATCH + b) * KNEI;

    union { unsigned u; float f; } lo, hi;
    unsigned u = Hd[(size_t)self * 192 + lane];
    lo.u = u << 16;            // col 2*lane
    hi.u = u & 0xffff0000u;    // col 2*lane+1
    float a0 = lo.f, a1 = hi.f;

    #pragma unroll
    for (int k = 0; k < KNEI; ++k) {
        unsigned v = Hd[(size_t)i0[k] * 192 + 64 + lane];
        lo.u = v << 16; hi.u = v & 0xffff0000u;
        a0 += lo.f; a1 += hi.f;
    }
    #pragma unroll
    for (int k = 0; k < KNEI; ++k) {
        unsigned v = Hd[(size_t)i1[k] * 192 + 128 + lane];
        lo.u = v << 16; hi.u = v & 0xffff0000u;
        a0 += lo.f; a1 += hi.f;
    }

    float2 r;
    r.x = a0 > 0.f ? a0 : 0.f;
    r.y = a1 > 0.f ? a1 : 0.f;
    ((float2*)(out + (size_t)b * HID))[lane] = r;
}

extern "C" void kernel_launch(void* const* d_in, const int* in_sizes, int n_in,
                              void* d_out, int out_size, void* d_ws, size_t ws_size,
                              hipStream_t stream) {
    const int*   nodes     = (const int*)d_in[0];
    const int*   neigh_idx = (const int*)d_in[1];
    const float* features  = (const float*)d_in[2];
    const float* W_stc     = (const float*)d_in[3];
    const float* W_det     = (const float*)d_in[4];
    float* out = (float*)d_out;

    // ws layout: Bsw 256*384*2B = 192KB (round to 256KB) | H 100000*384*2B = 76.8MB
    unsigned short* Bsw = (unsigned short*)d_ws;
    unsigned short* H   = (unsigned short*)((char*)d_ws + 256 * 1024);

    prep_W<<<34, 256, 0, stream>>>(W_stc, W_det, Bsw);
    gemm_H<<<(N_NODES + 63) / 64, 256, 0, stream>>>(features, Bsw, H);
    gather_out<<<(BATCH + 3) / 4, 256, 0, stream>>>(nodes, neigh_idx, H, out);
}

// Round 5
// 249.757 us; speedup vs baseline: 1.3966x; 1.3966x over previous
//
#include <hip/hip_runtime.h>
#include <hip/hip_bf16.h>

// Problem constants (from reference)
#define N_NODES 100000
#define FEAT    256
#define HID     128
#define REL     2
#define BATCH   20000
#define KNEI    10

// GEMM-H geometry: H[N_NODES][384] = features[N_NODES][256] @ Wall[256][384]
// Wall cols 0:128 = W_det[0:256]; cols 128+128r = (W_stc[r] @ W_det[256+128r:...]) / K
#define NCOL 384            // 24 n-tiles of 16
#define NT   24
#define KT   8              // 256 / 32
#define ASTRIDE 264         // 256 + 8 shorts pad for LDS A rows

typedef short bf16x8 __attribute__((ext_vector_type(8)));
typedef float f32x4  __attribute__((ext_vector_type(4)));

__device__ __forceinline__ unsigned short f2bf(float x) {
    union { float f; unsigned u; } v; v.f = x;
    unsigned r = v.u + 0x7fffu + ((v.u >> 16) & 1u);   // RNE
    return (unsigned short)(r >> 16);
}

__device__ __forceinline__ ushort4 pack4(float a, float b, float c, float d) {
    ushort4 p; p.x = f2bf(a); p.y = f2bf(b); p.z = f2bf(c); p.w = f2bf(d);
    return p;
}

// Swizzled index for logical (k in [0,256), n in [0,384)):
// fragment for (kt,nt) at Bsw[((kt*NT+nt)*64 + lane)*8 + j], 16B contiguous/lane
__device__ __forceinline__ size_t bsw_index(int k, int n) {
    int kt = k >> 5, j = k & 7, hi = (k >> 3) & 3;
    int lane = hi * 16 + (n & 15), nt = n >> 4;
    return ((size_t)(kt * NT + nt) * 64 + lane) * 8 + j;
}

// ---------------------------------------------------------------------------
// prep_W: build Wall[256][384] bf16 in MFMA B-swizzled layout.
// blocks 0..31 : cols 128+128r: (W_stc[r] @ W_det[256+128r:...]) * (1/K)
// blocks 32..33: cols 0:128   : copy of W_det rows 0..255
// ---------------------------------------------------------------------------
__global__ __launch_bounds__(256) void prep_W(const float* __restrict__ W_stc,
                                              const float* __restrict__ W_det,
                                              unsigned short* __restrict__ Bsw) {
    const int blk = blockIdx.x;
    const int tid = threadIdx.x;
    if (blk < 32) {
        const int rel   = blk >> 4;
        const int fbase = (blk & 15) * 16;
        const int n     = tid & 127;
        const int fh    = tid >> 7;
        const float* wd = W_det + (size_t)(256 + rel * HID) * HID + n;
        const float scale = 1.0f / (float)KNEI;   // fold neighbor mean here
        #pragma unroll
        for (int fo = 0; fo < 8; ++fo) {
            const int f = fbase + fh * 8 + fo;
            const float* ws = W_stc + (size_t)(rel * FEAT + f) * HID;
            float acc = 0.f;
            #pragma unroll 8
            for (int j2 = 0; j2 < HID; ++j2) acc += ws[j2] * wd[(size_t)j2 * HID];
            Bsw[bsw_index(f, 128 + rel * 128 + n)] = f2bf(acc * scale);
        }
    } else {
        const int base = (blk - 32) * 16384;
        #pragma unroll 4
        for (int i = 0; i < 64; ++i) {
            const int idx = base + i * 256 + tid;
            const int k = idx >> 7, n = idx & 127;
            Bsw[bsw_index(k, n)] = f2bf(W_det[idx]);
        }
    }
}

// ---------------------------------------------------------------------------
// gemm_H v2: per-kt B slices staged through LDS (fixes round-4's serialized
// global B-fragment loads). Block = 256 thr / 4 waves = 64 rows x 384 cols.
// Wave w: row-groups {2*(w>>1), 2*(w>>1)+1} x n-tiles [(w&1)*12, +12).
// LDS: A 33792 B + B-slice 24576 B = 58368 B -> 2 blocks/CU.
// ---------------------------------------------------------------------------
__global__ __launch_bounds__(256, 2) void gemm_H(const float* __restrict__ features,
                                                 const unsigned short* __restrict__ Bsw,
                                                 unsigned short* __restrict__ H) {
    __shared__ unsigned short Asm[64 * ASTRIDE];   // 33792 B
    __shared__ unsigned short Bs[NT * 64 * 8];     // 24576 B (one kt slice)

    const int row0 = blockIdx.x * 64;
    const int tid  = threadIdx.x;
    const float4* F4 = (const float4*)features;

    // Stage A: 64 rows x 64 float4, coalesced, fp32 -> bf16; clamp tail rows.
    #pragma unroll
    for (int i = 0; i < 16; ++i) {
        const int idx = i * 256 + tid;           // < 4096
        const int r   = idx >> 6;
        const int c4  = idx & 63;
        int rg = row0 + r;
        if (rg >= N_NODES) rg = N_NODES - 1;
        float4 v = F4[(size_t)rg * 64 + c4];
        *(ushort4*)(Asm + r * ASTRIDE + c4 * 4) = pack4(v.x, v.y, v.z, v.w);
    }

    const int w    = tid >> 6;
    const int lane = tid & 63;
    const int quad = lane >> 4;
    const int l16  = lane & 15;
    const int rga  = 2 * (w >> 1);               // row-group a (16 rows each)
    const int rgb  = rga + 1;
    const int ntb  = (w & 1) * 12;               // n-tile base

    const unsigned short* a0p = Asm + (rga * 16 + l16) * ASTRIDE + quad * 8;
    const unsigned short* a1p = Asm + (rgb * 16 + l16) * ASTRIDE + quad * 8;

    f32x4 acc0[12], acc1[12];
    #pragma unroll
    for (int nt = 0; nt < 12; ++nt) {
        acc0[nt] = (f32x4){0.f, 0.f, 0.f, 0.f};
        acc1[nt] = (f32x4){0.f, 0.f, 0.f, 0.f};
    }

    const int4* Bg  = (const int4*)Bsw;          // 16B chunks, slice = 1536 int4
    int4*       Bs4 = (int4*)Bs;

    for (int kt = 0; kt < KT; ++kt) {
        __syncthreads();                         // prev-iter Bs reads done (covers A-stage at kt=0)
        #pragma unroll
        for (int j = 0; j < 6; ++j)
            Bs4[j * 256 + tid] = Bg[(size_t)kt * 1536 + j * 256 + tid];
        __syncthreads();

        bf16x8 a0 = *(const bf16x8*)(a0p + kt * 32);
        bf16x8 a1 = *(const bf16x8*)(a1p + kt * 32);
        #pragma unroll
        for (int nt = 0; nt < 12; ++nt) {
            bf16x8 b = *(const bf16x8*)(Bs + ((ntb + nt) * 64 + lane) * 8);
            acc0[nt] = __builtin_amdgcn_mfma_f32_16x16x32_bf16(a0, b, acc0[nt], 0, 0, 0);
            acc1[nt] = __builtin_amdgcn_mfma_f32_16x16x32_bf16(a1, b, acc1[nt], 0, 0, 0);
        }
    }

    // Store H (bf16). C/D layout: col = l16, row = quad*4 + r.
    #pragma unroll
    for (int g = 0; g < 2; ++g) {
        const int rbase = row0 + (g ? rgb : rga) * 16 + quad * 4;
        #pragma unroll
        for (int r = 0; r < 4; ++r) {
            const int row = rbase + r;
            if (row < N_NODES) {
                unsigned short* hrow = H + (size_t)row * NCOL + ntb * 16 + l16;
                #pragma unroll
                for (int nt = 0; nt < 12; ++nt)
                    hrow[nt * 16] = f2bf(g ? acc1[nt][r] : acc0[nt][r]);
            }
        }
    }
}

// ---------------------------------------------------------------------------
// gather_out: out[b] = relu( H[self, 0:128] + sum_k H[idx0_k, 128:256]
//                                           + sum_k H[idx1_k, 256:384] )
// (mean scale folded into Wall). One wave per batch element; lane owns one
// dword (2 bf16 cols); each gather = 64 lanes x 4B = 256B coalesced chunk.
// ---------------------------------------------------------------------------
__global__ __launch_bounds__(256) void gather_out(const int* __restrict__ nodes,
                                                  const int* __restrict__ neigh_idx,
                                                  const unsigned short* __restrict__ H,
                                                  float* __restrict__ out) {
    const int w    = threadIdx.x >> 6;
    const int lane = threadIdx.x & 63;
    const int b    = blockIdx.x * 4 + w;
    if (b >= BATCH) return;

    const unsigned* Hd = (const unsigned*)H;       // row = 192 dwords
    const int self = nodes[b];
    const int* i0 = neigh_idx + (size_t)b * KNEI;
    const int* i1 = neigh_idx + (size_t)(BATCH + b) * KNEI;

    union { unsigned u; float f; } lo, hi;
    unsigned u = Hd[(size_t)self * 192 + lane];
    lo.u = u << 16;            // col 2*lane
    hi.u = u & 0xffff0000u;    // col 2*lane+1
    float a0 = lo.f, a1 = hi.f;

    #pragma unroll
    for (int k = 0; k < KNEI; ++k) {
        unsigned v = Hd[(size_t)i0[k] * 192 + 64 + lane];
        lo.u = v << 16; hi.u = v & 0xffff0000u;
        a0 += lo.f; a1 += hi.f;
    }
    #pragma unroll
    for (int k = 0; k < KNEI; ++k) {
        unsigned v = Hd[(size_t)i1[k] * 192 + 128 + lane];
        lo.u = v << 16; hi.u = v & 0xffff0000u;
        a0 += lo.f; a1 += hi.f;
    }

    float2 r;
    r.x = a0 > 0.f ? a0 : 0.f;
    r.y = a1 > 0.f ? a1 : 0.f;
    ((float2*)(out + (size_t)b * HID))[lane] = r;
}

extern "C" void kernel_launch(void* const* d_in, const int* in_sizes, int n_in,
                              void* d_out, int out_size, void* d_ws, size_t ws_size,
                              hipStream_t stream) {
    const int*   nodes     = (const int*)d_in[0];
    const int*   neigh_idx = (const int*)d_in[1];
    const float* features  = (const float*)d_in[2];
    const float* W_stc     = (const float*)d_in[3];
    const float* W_det     = (const float*)d_in[4];
    float* out = (float*)d_out;

    // ws layout: Bsw 256*384*2B = 192KB (round to 256KB) | H 100000*384*2B = 76.8MB
    unsigned short* Bsw = (unsigned short*)d_ws;
    unsigned short* H   = (unsigned short*)((char*)d_ws + 256 * 1024);

    prep_W<<<34, 256, 0, stream>>>(W_stc, W_det, Bsw);
    gemm_H<<<(N_NODES + 63) / 64, 256, 0, stream>>>(features, Bsw, H);
    gather_out<<<(BATCH + 3) / 4, 256, 0, stream>>>(nodes, neigh_idx, H, out);
}